// Round 1
// 454.473 us; speedup vs baseline: 1.0096x; 1.0096x over previous
//
#include <hip/hip_runtime.h>

// Cont_Loss: loss = sum((out[:,:,0:16:2] - target[:,:,1:16:2])^2) / 4194304
//
// Layout: [B*C=256][W=16][H*Wd=16384] fp32.
// pair p in [0,2048):  out  float idx = p*32768 + i          (even w-slice)
//                      tgt  float idx = p*32768 + 16384 + i  (odd  w-slice)
// float4 units: out = p*8192 + i4, tgt = p*8192 + 4096 + i4, i4 in [0,4096).
//
// Fixed geometry: 2048 blocks x 256 threads = 524288 threads; 8388608 float4
// pairs total -> exactly 16 sweeps/thread. 524288 = 128*4096, so i4 = g&4095
// is sweep-invariant and pair advances by 128/sweep (addr step = 1048576
// float4 = 16 MiB). Compile-time trip count -> full unroll, 8 loads in
// flight per 4-sweep batch.
//
// Reduction: NO atomics. Stage 1 plain-stores one partial per block into
// d_ws; stage 2 (1 block) reduces 2048 partials and overwrites the result
// (so no hipMemsetAsync needed either).

#define NBLOCKS   2048u
#define NTHREADS  256u
#define NSWEEPS   16u
#define SWEEP4    1048576u            // float4 index step per sweep (16 MiB)
#define INV_NORM  (1.0f / 4194304.0f)

__global__ __launch_bounds__(256) void cont_loss_stage1(
    const float* __restrict__ out_p,
    const float* __restrict__ tgt_p,
    float* __restrict__ partials)
{
    const float4* __restrict__ o4 = (const float4*)out_p;
    const float4* __restrict__ t4 = (const float4*)tgt_p;

    const unsigned g0   = blockIdx.x * NTHREADS + threadIdx.x;   // [0, 524288)
    const unsigned base = (g0 >> 12) * 8192u + (g0 & 4095u);     // float4 idx

    float acc[4] = {0.0f, 0.0f, 0.0f, 0.0f};

    #pragma unroll
    for (unsigned k = 0; k < NSWEEPS; k += 4) {
        float4 o_[4], t_[4];
        // issue all 8 loads of this batch before any use -> MLP
        #pragma unroll
        for (int j = 0; j < 4; ++j) {
            const unsigned off = base + (k + j) * SWEEP4;
            o_[j] = o4[off];
            t_[j] = t4[off + 4096u];
        }
        #pragma unroll
        for (int j = 0; j < 4; ++j) {
            const float dx = o_[j].x - t_[j].x;
            const float dy = o_[j].y - t_[j].y;
            const float dz = o_[j].z - t_[j].z;
            const float dw = o_[j].w - t_[j].w;
            acc[j] = fmaf(dx, dx, acc[j]);
            acc[j] = fmaf(dy, dy, acc[j]);
            acc[j] = fmaf(dz, dz, acc[j]);
            acc[j] = fmaf(dw, dw, acc[j]);
        }
    }

    float s = (acc[0] + acc[1]) + (acc[2] + acc[3]);

    // wave-64 shuffle reduction
    #pragma unroll
    for (int off = 32; off > 0; off >>= 1)
        s += __shfl_down(s, off, 64);

    __shared__ float wave_sums[4];   // 256 threads / 64 lanes
    const int lane = threadIdx.x & 63;
    const int wid  = threadIdx.x >> 6;
    if (lane == 0) wave_sums[wid] = s;
    __syncthreads();

    if (threadIdx.x == 0)
        partials[blockIdx.x] = (wave_sums[0] + wave_sums[1]) +
                               (wave_sums[2] + wave_sums[3]);
}

__global__ __launch_bounds__(256) void cont_loss_stage2(
    const float* __restrict__ partials,
    float* __restrict__ result)
{
    // 2048 partials / 256 threads = 8 each, coalesced (t + 256*j)
    float s = 0.0f;
    #pragma unroll
    for (int j = 0; j < 8; ++j)
        s += partials[threadIdx.x + j * 256];

    #pragma unroll
    for (int off = 32; off > 0; off >>= 1)
        s += __shfl_down(s, off, 64);

    __shared__ float wave_sums[4];
    const int lane = threadIdx.x & 63;
    const int wid  = threadIdx.x >> 6;
    if (lane == 0) wave_sums[wid] = s;
    __syncthreads();

    if (threadIdx.x == 0)
        result[0] = ((wave_sums[0] + wave_sums[1]) +
                     (wave_sums[2] + wave_sums[3])) * INV_NORM;
}

extern "C" void kernel_launch(void* const* d_in, const int* in_sizes, int n_in,
                              void* d_out, int out_size, void* d_ws, size_t ws_size,
                              hipStream_t stream)
{
    const float* out_p = (const float*)d_in[0];
    const float* tgt_p = (const float*)d_in[1];
    float* result   = (float*)d_out;
    float* partials = (float*)d_ws;   // needs 2048*4 = 8 KiB of workspace

    cont_loss_stage1<<<NBLOCKS, NTHREADS, 0, stream>>>(out_p, tgt_p, partials);
    cont_loss_stage2<<<1, NTHREADS, 0, stream>>>(partials, result);
}

// Round 2
// 434.058 us; speedup vs baseline: 1.0571x; 1.0470x over previous
//
#include <hip/hip_runtime.h>

// Cont_Loss: loss = sum((out[:,:,0:16:2] - target[:,:,1:16:2])^2) / 4194304
//
// Layout: [B*C=256][W=16][H*Wd=16384] fp32.
// pair p in [0,2048):  out  float idx = p*32768 + i          (even w-slice)
//                      tgt  float idx = p*32768 + 16384 + i  (odd  w-slice)
// float4 units: out = p*8192 + i4, tgt = p*8192 + 4096 + i4, i4 in [0,4096).
//
// Fixed geometry: 2048 blocks x 256 threads = 524288 threads; 8388608 float4
// pairs total -> exactly 16 sweeps/thread; i4 = g&4095 is sweep-invariant,
// pair advances 128/sweep (addr step = 1048576 float4 = 16 MiB).
//
// KEY (round 2): the harness poisons a 1-GiB workspace with fillBuffer every
// iteration, leaving L3/L2 full of DIRTY lines. Normal (allocating) reads
// evict those lines -> ~288 MB of forced writebacks billed to our kernel
// (268 MB read + 288 MB wb at ~4.2 TB/s mixed == the observed ~134 us).
// All stage-1 reads are therefore NON-TEMPORAL (no-allocate, `nt` flag):
// zero reuse in this kernel, so nt is free and stops the dirty evictions.
//
// Reduction: no atomics. Stage 1 plain-stores one partial per block into
// d_ws; stage 2 (1 block) reduces 2048 partials and overwrites the result.

#define NBLOCKS   2048u
#define NTHREADS  256u
#define NSWEEPS   16u
#define SWEEP4    1048576u            // float4 index step per sweep (16 MiB)
#define INV_NORM  (1.0f / 4194304.0f)

typedef float f32x4 __attribute__((ext_vector_type(4)));

__global__ __launch_bounds__(256) void cont_loss_stage1(
    const float* __restrict__ out_p,
    const float* __restrict__ tgt_p,
    float* __restrict__ partials)
{
    const f32x4* __restrict__ o4 = (const f32x4*)out_p;
    const f32x4* __restrict__ t4 = (const f32x4*)tgt_p;

    const unsigned g0   = blockIdx.x * NTHREADS + threadIdx.x;   // [0, 524288)
    const unsigned base = (g0 >> 12) * 8192u + (g0 & 4095u);     // float4 idx

    float acc[4] = {0.0f, 0.0f, 0.0f, 0.0f};

    #pragma unroll
    for (unsigned k = 0; k < NSWEEPS; k += 4) {
        f32x4 o_[4], t_[4];
        // issue all 8 nt loads of this batch before any use -> MLP
        #pragma unroll
        for (int j = 0; j < 4; ++j) {
            const unsigned off = base + (k + j) * SWEEP4;
            o_[j] = __builtin_nontemporal_load(o4 + off);
            t_[j] = __builtin_nontemporal_load(t4 + off + 4096u);
        }
        #pragma unroll
        for (int j = 0; j < 4; ++j) {
            const float dx = o_[j].x - t_[j].x;
            const float dy = o_[j].y - t_[j].y;
            const float dz = o_[j].z - t_[j].z;
            const float dw = o_[j].w - t_[j].w;
            acc[j] = fmaf(dx, dx, acc[j]);
            acc[j] = fmaf(dy, dy, acc[j]);
            acc[j] = fmaf(dz, dz, acc[j]);
            acc[j] = fmaf(dw, dw, acc[j]);
        }
    }

    float s = (acc[0] + acc[1]) + (acc[2] + acc[3]);

    // wave-64 shuffle reduction
    #pragma unroll
    for (int off = 32; off > 0; off >>= 1)
        s += __shfl_down(s, off, 64);

    __shared__ float wave_sums[4];   // 256 threads / 64 lanes
    const int lane = threadIdx.x & 63;
    const int wid  = threadIdx.x >> 6;
    if (lane == 0) wave_sums[wid] = s;
    __syncthreads();

    if (threadIdx.x == 0)
        partials[blockIdx.x] = (wave_sums[0] + wave_sums[1]) +
                               (wave_sums[2] + wave_sums[3]);
}

__global__ __launch_bounds__(256) void cont_loss_stage2(
    const float* __restrict__ partials,
    float* __restrict__ result)
{
    // 2048 partials / 256 threads = 8 each, coalesced (t + 256*j)
    float s = 0.0f;
    #pragma unroll
    for (int j = 0; j < 8; ++j)
        s += partials[threadIdx.x + j * 256];

    #pragma unroll
    for (int off = 32; off > 0; off >>= 1)
        s += __shfl_down(s, off, 64);

    __shared__ float wave_sums[4];
    const int lane = threadIdx.x & 63;
    const int wid  = threadIdx.x >> 6;
    if (lane == 0) wave_sums[wid] = s;
    __syncthreads();

    if (threadIdx.x == 0)
        result[0] = ((wave_sums[0] + wave_sums[1]) +
                     (wave_sums[2] + wave_sums[3])) * INV_NORM;
}

extern "C" void kernel_launch(void* const* d_in, const int* in_sizes, int n_in,
                              void* d_out, int out_size, void* d_ws, size_t ws_size,
                              hipStream_t stream)
{
    const float* out_p = (const float*)d_in[0];
    const float* tgt_p = (const float*)d_in[1];
    float* result   = (float*)d_out;
    float* partials = (float*)d_ws;   // needs 2048*4 = 8 KiB of workspace

    cont_loss_stage1<<<NBLOCKS, NTHREADS, 0, stream>>>(out_p, tgt_p, partials);
    cont_loss_stage2<<<1, NTHREADS, 0, stream>>>(partials, result);
}